// Round 2
// baseline (249.040 us; speedup 1.0000x reference)
//
#include <hip/hip_runtime.h>

#define NB   4
#define NH   32
#define ND   128
#define NHID 4096
#define NSQ  4096
#define NSF  63
#define NST  4160      // NSQ + NSF + 1
#define NBH  128       // NB * NH

// ---------------------------------------------------------------------------
// GEMV: Y[b, j] = sum_i X[b, i] * W[j, i]   (W row-major HIDxHID)
// 8 rows per block, 4 batches simultaneously; X tile staged in LDS.
// grid = 4096/8 = 512 blocks, 256 threads.
// ---------------------------------------------------------------------------
__global__ __launch_bounds__(256) void gemv8_kernel(const float* __restrict__ W,
                                                    const float* __restrict__ X,
                                                    float* __restrict__ Y) {
    __shared__ float4 xs[4][256];
    __shared__ float  wred[32][4];
    const int tid  = threadIdx.x;
    const int row0 = blockIdx.x * 8;

    float acc[8][4];
#pragma unroll
    for (int r = 0; r < 8; ++r)
#pragma unroll
        for (int b = 0; b < 4; ++b) acc[r][b] = 0.f;

    for (int kt = 0; kt < 4; ++kt) {
        const int kb = kt * 1024;
#pragma unroll
        for (int b = 0; b < 4; ++b)
            xs[b][tid] = *(const float4*)(&X[b * NHID + kb + tid * 4]);
        __syncthreads();
#pragma unroll
        for (int r = 0; r < 8; ++r) {
            float4 w = *(const float4*)(&W[(size_t)(row0 + r) * NHID + kb + tid * 4]);
#pragma unroll
            for (int b = 0; b < 4; ++b) {
                float4 x = xs[b][tid];
                acc[r][b] += w.x * x.x + w.y * x.y + w.z * x.z + w.w * x.w;
            }
        }
        __syncthreads();
    }

    const int lane = tid & 63, wave = tid >> 6;
#pragma unroll
    for (int o = 0; o < 32; ++o) {
        float v = acc[o >> 2][o & 3];
#pragma unroll
        for (int off = 32; off; off >>= 1) v += __shfl_down(v, off, 64);
        if (lane == 0) wred[o][wave] = v;
    }
    __syncthreads();
    if (tid < 32) {
        float v = wred[tid][0] + wred[tid][1] + wred[tid][2] + wred[tid][3];
        Y[(size_t)(tid & 3) * NHID + row0 + (tid >> 2)] = v;
    }
}

// ---------------------------------------------------------------------------
// RoPE on q,k + low-rank qr[bh][r] = sum_d q_rope[d] * key_q[bh,d,r]
// grid = 128 (bh), 128 threads (d)
// ---------------------------------------------------------------------------
__global__ __launch_bounds__(128) void rope_qr_kernel(const float* __restrict__ qraw,
                                                      const float* __restrict__ kraw,
                                                      const int*   __restrict__ pos_ids,
                                                      const float* __restrict__ key_q,
                                                      float* __restrict__ qrope,
                                                      float* __restrict__ krope,
                                                      float* __restrict__ qr) {
    const int bh = blockIdx.x;
    const int b  = bh >> 5;
    const int d  = threadIdx.x;
    const int base = bh * ND;

    const double pos  = (double)pos_ids[b];              // QL == 1
    const int    j    = d & 63;
    const double invf = pow(10000.0, -(double)(2 * j) / 128.0);
    const double ang  = pos * invf;
    const float  c = (float)cos(ang), s = (float)sin(ang);

    const float qv = qraw[base + d], kv = kraw[base + d];
    const float qh = (d < 64) ? -qraw[base + d + 64] : qraw[base + d - 64];
    const float kh = (d < 64) ? -kraw[base + d + 64] : kraw[base + d - 64];
    const float qo = qv * c + qh * s;
    const float ko = kv * c + kh * s;
    qrope[base + d] = qo;
    krope[base + d] = ko;

    __shared__ float4 red[128];
    float4 kq = *(const float4*)(&key_q[(size_t)(base + d) * 4]);
    red[d] = make_float4(qo * kq.x, qo * kq.y, qo * kq.z, qo * kq.w);
    __syncthreads();
    for (int st = 64; st; st >>= 1) {
        if (d < st) {
            red[d].x += red[d + st].x; red[d].y += red[d + st].y;
            red[d].z += red[d + st].z; red[d].w += red[d + st].w;
        }
        __syncthreads();
    }
    if (d == 0) *(float4*)(&qr[bh * 4]) = red[0];
}

// ---------------------------------------------------------------------------
// Quantized-K scores: scores[bh, s] for s in [0, NSQ)
//   = ( sum_d q[d]*(code*scale+mn) + qr . key_p[s] ) / sqrt(D)
// grid = NBH*16 (chunks of 256 s), 256 threads.
// ---------------------------------------------------------------------------
__global__ __launch_bounds__(256) void scores_quant_kernel(const int*   __restrict__ kq,
                                                           const float* __restrict__ ksc,
                                                           const float* __restrict__ kmn,
                                                           const float* __restrict__ keyp,
                                                           const float* __restrict__ qrope,
                                                           const float* __restrict__ qr,
                                                           float* __restrict__ scores) {
    const int bh    = blockIdx.x >> 4;
    const int chunk = blockIdx.x & 15;
    const int tid   = threadIdx.x;
    const int gbase = chunk * 4;   // group index base (4 groups of 64 per chunk)

    __shared__ float4 qs[128];     // q[d] * scale[d][gbase..gbase+3]
    __shared__ float4 mred[128];
    __shared__ float  qmn[4];

    if (tid < 128) {
        const int d = tid;
        const float q = qrope[bh * ND + d];
        float4 sc = *(const float4*)(&ksc[((size_t)bh * ND + d) * 64 + gbase]);
        qs[d] = make_float4(q * sc.x, q * sc.y, q * sc.z, q * sc.w);
        float4 mn = *(const float4*)(&kmn[((size_t)bh * ND + d) * 64 + gbase]);
        mred[d] = make_float4(q * mn.x, q * mn.y, q * mn.z, q * mn.w);
    }
    __syncthreads();
    for (int st = 64; st; st >>= 1) {
        if (tid < st) {
            mred[tid].x += mred[tid + st].x; mred[tid].y += mred[tid + st].y;
            mred[tid].z += mred[tid + st].z; mred[tid].w += mred[tid + st].w;
        }
        __syncthreads();
    }
    if (tid == 0) { qmn[0] = mred[0].x; qmn[1] = mred[0].y; qmn[2] = mred[0].z; qmn[3] = mred[0].w; }
    __syncthreads();

    const int s = chunk * 256 + tid;
    const int g = tid >> 6;
    const int* kcol = kq + (size_t)bh * ND * NSQ + s;

    float acc = 0.f;
#pragma unroll 8
    for (int d = 0; d < ND; ++d) {
        const int code = kcol[(size_t)d * NSQ];
        const float w = ((const float*)&qs[d])[g];
        acc += w * (float)code;
    }
    acc += qmn[g];

    float4 kp = *(const float4*)(&keyp[((size_t)bh * NSQ + s) * 4]);
    float4 q4 = *(const float4*)(&qr[bh * 4]);
    acc += q4.x * kp.x + q4.y * kp.y + q4.z * kp.z + q4.w * kp.w;

    scores[(size_t)bh * NST + s] = acc * 0.08838834764831845f; // 1/sqrt(128)
}

// ---------------------------------------------------------------------------
// Full-precision tail scores: s in [NSQ, NSQ+64): k_full rows 0..62, then new k
// grid = 128 (bh), 256 threads (4 waves, each wave does 16 scores)
// ---------------------------------------------------------------------------
__global__ __launch_bounds__(256) void scores_full_kernel(const float* __restrict__ kfull,
                                                          const float* __restrict__ krope,
                                                          const float* __restrict__ qrope,
                                                          float* __restrict__ scores) {
    const int bh   = blockIdx.x;
    const int tid  = threadIdx.x;
    const int lane = tid & 63, wave = tid >> 6;
    __shared__ float qsh[128];
    if (tid < 128) qsh[tid] = qrope[bh * ND + tid];
    __syncthreads();

    for (int t = wave; t < 64; t += 4) {
        const float* row = (t < 63) ? &kfull[((size_t)bh * NSF + t) * ND]
                                    : &krope[bh * ND];
        const int d = lane * 2;
        float v = qsh[d] * row[d] + qsh[d + 1] * row[d + 1];
#pragma unroll
        for (int off = 32; off; off >>= 1) v += __shfl_down(v, off, 64);
        if (lane == 0) scores[(size_t)bh * NST + NSQ + t] = v * 0.08838834764831845f;
    }
}

// ---------------------------------------------------------------------------
// Softmax over 4160 per (bh), in place. grid = 128, 256 threads.
// ---------------------------------------------------------------------------
__global__ __launch_bounds__(256) void softmax_kernel(float* __restrict__ scores) {
    const int bh = blockIdx.x;
    const int tid = threadIdx.x;
    float* row = scores + (size_t)bh * NST;
    __shared__ float red[256];

    float m = -1e30f;
    for (int i = tid; i < NST; i += 256) m = fmaxf(m, row[i]);
    red[tid] = m; __syncthreads();
    for (int st = 128; st; st >>= 1) { if (tid < st) red[tid] = fmaxf(red[tid], red[tid + st]); __syncthreads(); }
    m = red[0]; __syncthreads();

    float sum = 0.f;
    for (int i = tid; i < NST; i += 256) { float e = expf(row[i] - m); row[i] = e; sum += e; }
    red[tid] = sum; __syncthreads();
    for (int st = 128; st; st >>= 1) { if (tid < st) red[tid] += red[tid + st]; __syncthreads(); }
    const float inv = 1.f / red[0];
    __syncthreads();
    for (int i = tid; i < NST; i += 256) row[i] *= inv;
}

// ---------------------------------------------------------------------------
// Quantized-V partial accumulation + partial low-rank pr.
// grid = NBH*16 (splits of 256 s-rows), 128 threads (d).
// ---------------------------------------------------------------------------
__global__ __launch_bounds__(128) void pv_quant_kernel(const int*   __restrict__ vq,
                                                       const float* __restrict__ vsc,
                                                       const float* __restrict__ vmn,
                                                       const float* __restrict__ valq,
                                                       const float* __restrict__ probs,
                                                       float* __restrict__ pout,
                                                       float* __restrict__ ppr) {
    const int bh    = blockIdx.x >> 4;
    const int split = blockIdx.x & 15;
    const int tid   = threadIdx.x;     // d
    const int sbase = split * 256;
    const int g     = tid >> 6;

    const float* p     = probs + (size_t)bh * NST;
    const int*   vrow  = vq  + ((size_t)bh * NSQ + sbase) * ND;
    const float* scrow = vsc + ((size_t)bh * NSQ + sbase) * 2;
    const float* mnrow = vmn + ((size_t)bh * NSQ + sbase) * 2;

    float acc = 0.f;
#pragma unroll 4
    for (int k = 0; k < 256; ++k) {
        const float pv   = p[sbase + k];
        const int   code = vrow[(size_t)k * ND + tid];
        const float sc   = scrow[k * 2 + g];
        const float mn   = mnrow[k * 2 + g];
        acc += pv * ((float)code * sc + mn);
    }
    pout[((size_t)bh * 16 + split) * ND + tid] = acc;

    // partial pr[r] = sum_s p[s] * value_q[bh, s, r]
    float4 pr = make_float4(0.f, 0.f, 0.f, 0.f);
#pragma unroll
    for (int k = 0; k < 2; ++k) {
        const int s = sbase + tid + 128 * k;
        const float pv = p[s];
        float4 v4 = *(const float4*)(&valq[((size_t)bh * NSQ + s) * 4]);
        pr.x += pv * v4.x; pr.y += pv * v4.y; pr.z += pv * v4.z; pr.w += pv * v4.w;
    }
    __shared__ float4 red[128];
    red[tid] = pr; __syncthreads();
    for (int st = 64; st; st >>= 1) {
        if (tid < st) {
            red[tid].x += red[tid + st].x; red[tid].y += red[tid + st].y;
            red[tid].z += red[tid + st].z; red[tid].w += red[tid + st].w;
        }
        __syncthreads();
    }
    if (tid == 0) *(float4*)(&ppr[((size_t)bh * 16 + split) * 4]) = red[0];
}

// ---------------------------------------------------------------------------
// Finish: reduce split partials, add low-rank V and full-precision V tail.
// grid = 128 (bh), 128 threads (d).
// ---------------------------------------------------------------------------
__global__ __launch_bounds__(128) void pv_finish_kernel(const float* __restrict__ pout,
                                                        const float* __restrict__ ppr,
                                                        const float* __restrict__ valp,
                                                        const float* __restrict__ vfull,
                                                        const float* __restrict__ vraw,
                                                        const float* __restrict__ probs,
                                                        float* __restrict__ attn_out) {
    const int bh = blockIdx.x;
    const int d  = threadIdx.x;

    float acc = 0.f;
#pragma unroll
    for (int sp = 0; sp < 16; ++sp) acc += pout[((size_t)bh * 16 + sp) * ND + d];

    float prx = 0.f, pry = 0.f, prz = 0.f, prw = 0.f;
#pragma unroll
    for (int sp = 0; sp < 16; ++sp) {
        float4 t = *(const float4*)(&ppr[((size_t)bh * 16 + sp) * 4]);
        prx += t.x; pry += t.y; prz += t.z; prw += t.w;
    }
    float4 vp = *(const float4*)(&valp[((size_t)bh * ND + d) * 4]);
    acc += prx * vp.x + pry * vp.y + prz * vp.z + prw * vp.w;

    const float* pf = probs + (size_t)bh * NST + NSQ;
    for (int t = 0; t < NSF; ++t) acc += pf[t] * vfull[((size_t)bh * NSF + t) * ND + d];
    acc += pf[NSF] * vraw[bh * ND + d];

    attn_out[bh * ND + d] = acc;
}

// ---------------------------------------------------------------------------
extern "C" void kernel_launch(void* const* d_in, const int* in_sizes, int n_in,
                              void* d_out, int out_size, void* d_ws, size_t ws_size,
                              hipStream_t stream) {
    const float* hs    = (const float*)d_in[0];
    const float* wq    = (const float*)d_in[1];
    const float* wk    = (const float*)d_in[2];
    const float* wv    = (const float*)d_in[3];
    const float* wo    = (const float*)d_in[4];
    const int*   pos   = (const int*)  d_in[5];
    const int*   kq    = (const int*)  d_in[6];
    const float* ksc   = (const float*)d_in[7];
    const float* kmn   = (const float*)d_in[8];
    const float* kfull = (const float*)d_in[9];
    const float* keyp  = (const float*)d_in[10];
    const float* keyq  = (const float*)d_in[11];
    const int*   vq    = (const int*)  d_in[12];
    const float* vsc   = (const float*)d_in[13];
    const float* vmn   = (const float*)d_in[14];
    const float* vfull = (const float*)d_in[15];
    const float* valq  = (const float*)d_in[16];
    const float* valp  = (const float*)d_in[17];

    float* ws = (float*)d_ws;
    float* q_raw   = ws;                 // 16384
    float* k_raw   = q_raw  + 16384;     // 16384
    float* v_raw   = k_raw  + 16384;     // 16384
    float* q_rope  = v_raw  + 16384;     // 16384
    float* k_rope  = q_rope + 16384;     // 16384
    float* qr      = k_rope + 16384;     // 512
    float* scores  = qr     + 512;       // 128*4160 = 532480
    float* pout    = scores + 532480;    // 128*16*128 = 262144
    float* ppr     = pout   + 262144;    // 128*16*4 = 8192
    float* attno   = ppr    + 8192;      // 16384

    gemv8_kernel<<<512, 256, 0, stream>>>(wq, hs, q_raw);
    gemv8_kernel<<<512, 256, 0, stream>>>(wk, hs, k_raw);
    gemv8_kernel<<<512, 256, 0, stream>>>(wv, hs, v_raw);

    rope_qr_kernel<<<128, 128, 0, stream>>>(q_raw, k_raw, pos, keyq, q_rope, k_rope, qr);

    scores_quant_kernel<<<2048, 256, 0, stream>>>(kq, ksc, kmn, keyp, q_rope, qr, scores);
    scores_full_kernel<<<128, 256, 0, stream>>>(kfull, k_rope, q_rope, scores);

    softmax_kernel<<<128, 256, 0, stream>>>(scores);

    pv_quant_kernel<<<2048, 128, 0, stream>>>(vq, vsc, vmn, valq, scores, pout, ppr);
    pv_finish_kernel<<<128, 128, 0, stream>>>(pout, ppr, valp, vfull, v_raw, scores, attno);

    gemv8_kernel<<<512, 256, 0, stream>>>(wo, attno, (float*)d_out);
}

// Round 3
// 219.203 us; speedup vs baseline: 1.1361x; 1.1361x over previous
//
#include <hip/hip_runtime.h>

#define NB   4
#define NH   32
#define ND   128
#define NHID 4096
#define NSQ  4096
#define NSF  63
#define NST  4160      // NSQ + NSF + 1
#define NBH  128       // NB * NH

// ---------------------------------------------------------------------------
// GEMV: Y[b, j] = sum_i X[b, i] * W[j, i]   (W row-major HIDxHID)
// 8 rows per block, 4 batches simultaneously; X tile staged in LDS.
// 512 blocks per matrix, 256 threads.
// ---------------------------------------------------------------------------
__device__ __forceinline__ void gemv8_body(const float* __restrict__ W,
                                           const float* __restrict__ X,
                                           float* __restrict__ Y,
                                           int blk) {
    __shared__ float4 xs[4][256];
    __shared__ float  wred[32][4];
    const int tid  = threadIdx.x;
    const int row0 = blk * 8;

    float acc[8][4];
#pragma unroll
    for (int r = 0; r < 8; ++r)
#pragma unroll
        for (int b = 0; b < 4; ++b) acc[r][b] = 0.f;

    for (int kt = 0; kt < 4; ++kt) {
        const int kb = kt * 1024;
#pragma unroll
        for (int b = 0; b < 4; ++b)
            xs[b][tid] = *(const float4*)(&X[b * NHID + kb + tid * 4]);
        __syncthreads();
#pragma unroll
        for (int r = 0; r < 8; ++r) {
            float4 w = *(const float4*)(&W[(size_t)(row0 + r) * NHID + kb + tid * 4]);
#pragma unroll
            for (int b = 0; b < 4; ++b) {
                float4 x = xs[b][tid];
                acc[r][b] += w.x * x.x + w.y * x.y + w.z * x.z + w.w * x.w;
            }
        }
        __syncthreads();
    }

    const int lane = tid & 63, wave = tid >> 6;
#pragma unroll
    for (int o = 0; o < 32; ++o) {
        float v = acc[o >> 2][o & 3];
#pragma unroll
        for (int off = 32; off; off >>= 1) v += __shfl_down(v, off, 64);
        if (lane == 0) wred[o][wave] = v;
    }
    __syncthreads();
    if (tid < 32) {
        float v = wred[tid][0] + wred[tid][1] + wred[tid][2] + wred[tid][3];
        Y[(size_t)(tid & 3) * NHID + row0 + (tid >> 2)] = v;
    }
}

__global__ __launch_bounds__(256) void gemv8_kernel(const float* __restrict__ W,
                                                    const float* __restrict__ X,
                                                    float* __restrict__ Y) {
    gemv8_body(W, X, Y, blockIdx.x);
}

// grid = 1536: blocks [0,512) -> wq, [512,1024) -> wk, [1024,1536) -> wv
__global__ __launch_bounds__(256) void gemv8_qkv_kernel(const float* __restrict__ wq,
                                                        const float* __restrict__ wk,
                                                        const float* __restrict__ wv,
                                                        const float* __restrict__ X,
                                                        float* __restrict__ q,
                                                        float* __restrict__ k,
                                                        float* __restrict__ v) {
    const int which = blockIdx.x >> 9;
    const int blk   = blockIdx.x & 511;
    const float* W = (which == 0) ? wq : (which == 1) ? wk : wv;
    float*       Y = (which == 0) ? q  : (which == 1) ? k  : v;
    gemv8_body(W, X, Y, blk);
}

// ---------------------------------------------------------------------------
// RoPE on q,k + low-rank qr + full-precision tail scores.
// grid = 128 (bh), 256 threads.
// ---------------------------------------------------------------------------
__global__ __launch_bounds__(256) void rope_full_kernel(const float* __restrict__ qraw,
                                                        const float* __restrict__ kraw,
                                                        const int*   __restrict__ pos_ids,
                                                        const float* __restrict__ key_q,
                                                        const float* __restrict__ kfull,
                                                        float* __restrict__ qrope,
                                                        float* __restrict__ qr,
                                                        float* __restrict__ scores) {
    const int bh   = blockIdx.x;
    const int b    = bh >> 5;
    const int tid  = threadIdx.x;
    const int base = bh * ND;

    __shared__ float  qsh[128], ksh[128];
    __shared__ float4 red[128];

    if (tid < 128) {
        const int d = tid;
        const double pos  = (double)pos_ids[b];              // QL == 1
        const int    j    = d & 63;
        const double invf = pow(10000.0, -(double)(2 * j) / 128.0);
        const double ang  = pos * invf;
        const float  c = (float)cos(ang), s = (float)sin(ang);

        const float qv = qraw[base + d], kv = kraw[base + d];
        const float qh = (d < 64) ? -qraw[base + d + 64] : qraw[base + d - 64];
        const float kh = (d < 64) ? -kraw[base + d + 64] : kraw[base + d - 64];
        const float qo = qv * c + qh * s;
        const float ko = kv * c + kh * s;
        qrope[base + d] = qo;
        qsh[d] = qo;
        ksh[d] = ko;

        float4 kq = *(const float4*)(&key_q[(size_t)(base + d) * 4]);
        red[d] = make_float4(qo * kq.x, qo * kq.y, qo * kq.z, qo * kq.w);
    }
    __syncthreads();
    for (int st = 64; st; st >>= 1) {
        if (tid < st) {
            red[tid].x += red[tid + st].x; red[tid].y += red[tid + st].y;
            red[tid].z += red[tid + st].z; red[tid].w += red[tid + st].w;
        }
        __syncthreads();
    }
    if (tid == 0) *(float4*)(&qr[bh * 4]) = red[0];

    // tail scores: s in [NSQ, NSQ+64)
    const int lane = tid & 63, wave = tid >> 6;
    for (int t = wave; t < 64; t += 4) {
        const float* row = (t < 63) ? &kfull[((size_t)bh * NSF + t) * ND] : ksh;
        const int d = lane * 2;
        float v = qsh[d] * row[d] + qsh[d + 1] * row[d + 1];
#pragma unroll
        for (int off = 32; off; off >>= 1) v += __shfl_down(v, off, 64);
        if (lane == 0) scores[(size_t)bh * NST + NSQ + t] = v * 0.08838834764831845f;
    }
}

// ---------------------------------------------------------------------------
// Quantized-K scores. Each thread: 4 consecutive s via int4 loads.
// grid = NBH*4 (chunks of 1024 s), 256 threads.
// ---------------------------------------------------------------------------
__global__ __launch_bounds__(256) void scores_quant_kernel(const int*   __restrict__ kq,
                                                           const float* __restrict__ ksc,
                                                           const float* __restrict__ kmn,
                                                           const float* __restrict__ keyp,
                                                           const float* __restrict__ qrope,
                                                           const float* __restrict__ qr,
                                                           float* __restrict__ scores) {
    const int bh    = blockIdx.x >> 2;
    const int chunk = blockIdx.x & 3;
    const int tid   = threadIdx.x;
    const int gbase = chunk * 16;      // 16 groups of 64 per 1024-s chunk

    __shared__ float qs[128][16];      // q[d] * scale[d][g]
    __shared__ float mt[128][16];      // q[d] * mn[d][g] -> reduced over d

    {
        const int d = tid >> 1, half = tid & 1;
        const float q = qrope[bh * ND + d];
        const float* scp = &ksc[((size_t)bh * ND + d) * 64 + gbase + half * 8];
        const float* mnp = &kmn[((size_t)bh * ND + d) * 64 + gbase + half * 8];
        float4 a = *(const float4*)(scp);
        float4 c = *(const float4*)(scp + 4);
        qs[d][half * 8 + 0] = q * a.x; qs[d][half * 8 + 1] = q * a.y;
        qs[d][half * 8 + 2] = q * a.z; qs[d][half * 8 + 3] = q * a.w;
        qs[d][half * 8 + 4] = q * c.x; qs[d][half * 8 + 5] = q * c.y;
        qs[d][half * 8 + 6] = q * c.z; qs[d][half * 8 + 7] = q * c.w;
        float4 m0 = *(const float4*)(mnp);
        float4 m1 = *(const float4*)(mnp + 4);
        mt[d][half * 8 + 0] = q * m0.x; mt[d][half * 8 + 1] = q * m0.y;
        mt[d][half * 8 + 2] = q * m0.z; mt[d][half * 8 + 3] = q * m0.w;
        mt[d][half * 8 + 4] = q * m1.x; mt[d][half * 8 + 5] = q * m1.y;
        mt[d][half * 8 + 6] = q * m1.z; mt[d][half * 8 + 7] = q * m1.w;
    }
    __syncthreads();
    for (int st = 64; st; st >>= 1) {
        for (int idx = tid; idx < st * 16; idx += 256) {
            const int dd = idx >> 4, g = idx & 15;
            mt[dd][g] += mt[dd + st][g];
        }
        __syncthreads();
    }

    const int s0 = chunk * 1024 + tid * 4;
    const int g  = tid >> 4;           // (tid*4)/64
    const int* kcol = kq + (size_t)bh * ND * NSQ + s0;

    float a0 = 0.f, a1 = 0.f, a2 = 0.f, a3 = 0.f;
#pragma unroll 8
    for (int d = 0; d < ND; ++d) {
        int4 c = *(const int4*)(&kcol[(size_t)d * NSQ]);
        const float w = qs[d][g];
        a0 += w * (float)c.x; a1 += w * (float)c.y;
        a2 += w * (float)c.z; a3 += w * (float)c.w;
    }
    const float mnsum = mt[0][g];
    const float4 q4 = *(const float4*)(&qr[bh * 4]);

    float out[4] = {a0, a1, a2, a3};
#pragma unroll
    for (int j = 0; j < 4; ++j) {
        float4 kp = *(const float4*)(&keyp[((size_t)bh * NSQ + s0 + j) * 4]);
        out[j] = (out[j] + mnsum + q4.x * kp.x + q4.y * kp.y + q4.z * kp.z + q4.w * kp.w)
                 * 0.08838834764831845f;
    }
    *(float4*)(&scores[(size_t)bh * NST + s0]) = make_float4(out[0], out[1], out[2], out[3]);
}

// ---------------------------------------------------------------------------
// Softmax over 4160 per (bh), in place. grid = 128, 256 threads.
// ---------------------------------------------------------------------------
__global__ __launch_bounds__(256) void softmax_kernel(float* __restrict__ scores) {
    const int bh = blockIdx.x;
    const int tid = threadIdx.x;
    float* row = scores + (size_t)bh * NST;
    __shared__ float red[256];

    float m = -1e30f;
    for (int i = tid; i < NST; i += 256) m = fmaxf(m, row[i]);
    red[tid] = m; __syncthreads();
    for (int st = 128; st; st >>= 1) { if (tid < st) red[tid] = fmaxf(red[tid], red[tid + st]); __syncthreads(); }
    m = red[0]; __syncthreads();

    float sum = 0.f;
    for (int i = tid; i < NST; i += 256) { float e = expf(row[i] - m); row[i] = e; sum += e; }
    red[tid] = sum; __syncthreads();
    for (int st = 128; st; st >>= 1) { if (tid < st) red[tid] += red[tid + st]; __syncthreads(); }
    const float inv = 1.f / red[0];
    __syncthreads();
    for (int i = tid; i < NST; i += 256) row[i] *= inv;
}

// ---------------------------------------------------------------------------
// Quantized-V partials. 256 threads = 8 s-rows x 32 lanes, int4 along d.
// grid = NBH*16 (splits of 256 s), 256 threads.
// ---------------------------------------------------------------------------
__global__ __launch_bounds__(256) void pv_quant_kernel(const int*   __restrict__ vq,
                                                       const float* __restrict__ vsc,
                                                       const float* __restrict__ vmn,
                                                       const float* __restrict__ valq,
                                                       const float* __restrict__ probs,
                                                       float* __restrict__ pout,
                                                       float* __restrict__ ppr) {
    const int bh    = blockIdx.x >> 4;
    const int split = blockIdx.x & 15;
    const int tid   = threadIdx.x;
    const int sbase = split * 256;

    __shared__ float  psc[256][2];     // p[k] * scale[k][g]
    __shared__ float4 red4[256];       // -> ppr
    __shared__ float2 red2[256];       // -> pmn
    __shared__ float4 racc[256];
    __shared__ float  pmn2[2];

    {
        const int s = sbase + tid;
        const float pv = probs[(size_t)bh * NST + s];
        float2 sc = *(const float2*)(&vsc[((size_t)bh * NSQ + s) * 2]);
        float2 mn = *(const float2*)(&vmn[((size_t)bh * NSQ + s) * 2]);
        psc[tid][0] = pv * sc.x;
        psc[tid][1] = pv * sc.y;
        red2[tid] = make_float2(pv * mn.x, pv * mn.y);
        float4 v4 = *(const float4*)(&valq[((size_t)bh * NSQ + s) * 4]);
        red4[tid] = make_float4(pv * v4.x, pv * v4.y, pv * v4.z, pv * v4.w);
    }
    __syncthreads();
    for (int st = 128; st; st >>= 1) {
        if (tid < st) {
            red4[tid].x += red4[tid + st].x; red4[tid].y += red4[tid + st].y;
            red4[tid].z += red4[tid + st].z; red4[tid].w += red4[tid + st].w;
            red2[tid].x += red2[tid + st].x; red2[tid].y += red2[tid + st].y;
        }
        __syncthreads();
    }
    if (tid == 0) {
        *(float4*)(&ppr[((size_t)bh * 16 + split) * 4]) = red4[0];
        pmn2[0] = red2[0].x; pmn2[1] = red2[0].y;
    }

    const int r      = tid >> 5;       // s-row within group of 8
    const int lane32 = tid & 31;
    const int d4     = lane32 * 4;
    const int g      = lane32 >> 4;    // d4/64

    const int* vbase = vq + ((size_t)bh * NSQ + sbase) * ND + d4;

    float4 acc = make_float4(0.f, 0.f, 0.f, 0.f);
#pragma unroll 4
    for (int k0 = 0; k0 < 256; k0 += 8) {
        const int kk = k0 + r;
        int4 c = *(const int4*)(&vbase[(size_t)kk * ND]);
        const float w = psc[kk][g];
        acc.x += w * (float)c.x; acc.y += w * (float)c.y;
        acc.z += w * (float)c.z; acc.w += w * (float)c.w;
    }
    __syncthreads();                   // ensures tid0 consumed red4[0]/red2[0]
    racc[tid] = acc;
    __syncthreads();
    for (int st = 128; st >= 32; st >>= 1) {
        if (tid < st) {
            racc[tid].x += racc[tid + st].x; racc[tid].y += racc[tid + st].y;
            racc[tid].z += racc[tid + st].z; racc[tid].w += racc[tid + st].w;
        }
        __syncthreads();
    }
    if (tid < 32) {
        float4 t = racc[tid];
        const float mn = pmn2[tid >> 4];
        t.x += mn; t.y += mn; t.z += mn; t.w += mn;
        *(float4*)(&pout[((size_t)bh * 16 + split) * ND + tid * 4]) = t;
    }
}

// ---------------------------------------------------------------------------
// Finish: reduce split partials, add low-rank V and full-precision V tail.
// grid = 128 (bh), 128 threads (d).
// ---------------------------------------------------------------------------
__global__ __launch_bounds__(128) void pv_finish_kernel(const float* __restrict__ pout,
                                                        const float* __restrict__ ppr,
                                                        const float* __restrict__ valp,
                                                        const float* __restrict__ vfull,
                                                        const float* __restrict__ vraw,
                                                        const float* __restrict__ probs,
                                                        float* __restrict__ attn_out) {
    const int bh = blockIdx.x;
    const int d  = threadIdx.x;

    float acc = 0.f;
#pragma unroll
    for (int sp = 0; sp < 16; ++sp) acc += pout[((size_t)bh * 16 + sp) * ND + d];

    float prx = 0.f, pry = 0.f, prz = 0.f, prw = 0.f;
#pragma unroll
    for (int sp = 0; sp < 16; ++sp) {
        float4 t = *(const float4*)(&ppr[((size_t)bh * 16 + sp) * 4]);
        prx += t.x; pry += t.y; prz += t.z; prw += t.w;
    }
    float4 vp = *(const float4*)(&valp[((size_t)bh * ND + d) * 4]);
    acc += prx * vp.x + pry * vp.y + prz * vp.z + prw * vp.w;

    const float* pf = probs + (size_t)bh * NST + NSQ;
    for (int t = 0; t < NSF; ++t) acc += pf[t] * vfull[((size_t)bh * NSF + t) * ND + d];
    acc += pf[NSF] * vraw[bh * ND + d];

    attn_out[bh * ND + d] = acc;
}

// ---------------------------------------------------------------------------
extern "C" void kernel_launch(void* const* d_in, const int* in_sizes, int n_in,
                              void* d_out, int out_size, void* d_ws, size_t ws_size,
                              hipStream_t stream) {
    const float* hs    = (const float*)d_in[0];
    const float* wq    = (const float*)d_in[1];
    const float* wk    = (const float*)d_in[2];
    const float* wv    = (const float*)d_in[3];
    const float* wo    = (const float*)d_in[4];
    const int*   pos   = (const int*)  d_in[5];
    const int*   kq    = (const int*)  d_in[6];
    const float* ksc   = (const float*)d_in[7];
    const float* kmn   = (const float*)d_in[8];
    const float* kfull = (const float*)d_in[9];
    const float* keyp  = (const float*)d_in[10];
    const float* keyq  = (const float*)d_in[11];
    const int*   vq    = (const int*)  d_in[12];
    const float* vsc   = (const float*)d_in[13];
    const float* vmn   = (const float*)d_in[14];
    const float* vfull = (const float*)d_in[15];
    const float* valq  = (const float*)d_in[16];
    const float* valp  = (const float*)d_in[17];

    float* ws = (float*)d_ws;
    float* q_raw   = ws;                 // 16384
    float* k_raw   = q_raw  + 16384;     // 16384
    float* v_raw   = k_raw  + 16384;     // 16384
    float* q_rope  = v_raw  + 16384;     // 16384
    float* qr      = q_rope + 16384;     // 512
    float* scores  = qr     + 512;       // 128*4160 = 532480
    float* pout    = scores + 532480;    // 128*16*128 = 262144
    float* ppr     = pout   + 262144;    // 128*16*4 = 8192
    float* attno   = ppr    + 8192;      // 16384

    gemv8_qkv_kernel<<<1536, 256, 0, stream>>>(wq, wk, wv, hs, q_raw, k_raw, v_raw);

    rope_full_kernel<<<128, 256, 0, stream>>>(q_raw, k_raw, pos, keyq, kfull,
                                              q_rope, qr, scores);

    scores_quant_kernel<<<512, 256, 0, stream>>>(kq, ksc, kmn, keyp, q_rope, qr, scores);

    softmax_kernel<<<128, 256, 0, stream>>>(scores);

    pv_quant_kernel<<<2048, 256, 0, stream>>>(vq, vsc, vmn, valq, scores, pout, ppr);
    pv_finish_kernel<<<128, 128, 0, stream>>>(pout, ppr, valp, vfull, v_raw, scores, attno);

    gemv8_kernel<<<512, 256, 0, stream>>>(wo, attno, (float*)d_out);
}

// Round 4
// 199.736 us; speedup vs baseline: 1.2468x; 1.0975x over previous
//
#include <hip/hip_runtime.h>

#define NB   4
#define NH   32
#define ND   128
#define NHID 4096
#define NSQ  4096
#define NSF  63
#define NST  4160      // NSQ + NSF + 1
#define NBH  128       // NB * NH

typedef int   v4i __attribute__((ext_vector_type(4)));
typedef float v4f __attribute__((ext_vector_type(4)));

// ---------------------------------------------------------------------------
// GEMV: Y[b, j] = sum_i X[b, i] * W[j, i]   (W row-major HIDxHID)
// 8 rows per block, 4 batches simultaneously; X tile staged in LDS.
// 512 blocks per matrix, 256 threads. Weight stream is read-once -> nt loads.
// ---------------------------------------------------------------------------
__device__ __forceinline__ void gemv8_body(const float* __restrict__ W,
                                           const float* __restrict__ X,
                                           float* __restrict__ Y,
                                           int blk) {
    __shared__ float4 xs[4][256];
    __shared__ float  wred[32][4];
    const int tid  = threadIdx.x;
    const int row0 = blk * 8;

    float acc[8][4];
#pragma unroll
    for (int r = 0; r < 8; ++r)
#pragma unroll
        for (int b = 0; b < 4; ++b) acc[r][b] = 0.f;

    for (int kt = 0; kt < 4; ++kt) {
        const int kb = kt * 1024;
#pragma unroll
        for (int b = 0; b < 4; ++b)
            xs[b][tid] = *(const float4*)(&X[b * NHID + kb + tid * 4]);
        __syncthreads();
#pragma unroll
        for (int r = 0; r < 8; ++r) {
            v4f w = __builtin_nontemporal_load(
                        (const v4f*)&W[(size_t)(row0 + r) * NHID + kb + tid * 4]);
#pragma unroll
            for (int b = 0; b < 4; ++b) {
                float4 x = xs[b][tid];
                acc[r][b] += w.x * x.x + w.y * x.y + w.z * x.z + w.w * x.w;
            }
        }
        __syncthreads();
    }

    const int lane = tid & 63, wave = tid >> 6;
#pragma unroll
    for (int o = 0; o < 32; ++o) {
        float v = acc[o >> 2][o & 3];
#pragma unroll
        for (int off = 32; off; off >>= 1) v += __shfl_down(v, off, 64);
        if (lane == 0) wred[o][wave] = v;
    }
    __syncthreads();
    if (tid < 32) {
        float v = wred[tid][0] + wred[tid][1] + wred[tid][2] + wred[tid][3];
        Y[(size_t)(tid & 3) * NHID + row0 + (tid >> 2)] = v;
    }
}

__global__ __launch_bounds__(256) void gemv8_kernel(const float* __restrict__ W,
                                                    const float* __restrict__ X,
                                                    float* __restrict__ Y) {
    gemv8_body(W, X, Y, blockIdx.x);
}

// grid = 1536: blocks [0,512) -> wq, [512,1024) -> wk, [1024,1536) -> wv
__global__ __launch_bounds__(256) void gemv8_qkv_kernel(const float* __restrict__ wq,
                                                        const float* __restrict__ wk,
                                                        const float* __restrict__ wv,
                                                        const float* __restrict__ X,
                                                        float* __restrict__ q,
                                                        float* __restrict__ k,
                                                        float* __restrict__ v) {
    const int which = blockIdx.x >> 9;
    const int blk   = blockIdx.x & 511;
    const float* W = (which == 0) ? wq : (which == 1) ? wk : wv;
    float*       Y = (which == 0) ? q  : (which == 1) ? k  : v;
    gemv8_body(W, X, Y, blk);
}

// ---------------------------------------------------------------------------
// RoPE on q,k + low-rank qr + full-precision tail scores.
// grid = 128 (bh), 256 threads.
// ---------------------------------------------------------------------------
__global__ __launch_bounds__(256) void rope_full_kernel(const float* __restrict__ qraw,
                                                        const float* __restrict__ kraw,
                                                        const int*   __restrict__ pos_ids,
                                                        const float* __restrict__ key_q,
                                                        const float* __restrict__ kfull,
                                                        float* __restrict__ qrope,
                                                        float* __restrict__ qr,
                                                        float* __restrict__ scores) {
    const int bh   = blockIdx.x;
    const int b    = bh >> 5;
    const int tid  = threadIdx.x;
    const int base = bh * ND;

    __shared__ float  qsh[128], ksh[128];
    __shared__ float4 red[128];

    if (tid < 128) {
        const int d = tid;
        const double pos  = (double)pos_ids[b];              // QL == 1
        const int    j    = d & 63;
        const double invf = pow(10000.0, -(double)(2 * j) / 128.0);
        const double ang  = pos * invf;
        const float  c = (float)cos(ang), s = (float)sin(ang);

        const float qv = qraw[base + d], kv = kraw[base + d];
        const float qh = (d < 64) ? -qraw[base + d + 64] : qraw[base + d - 64];
        const float kh = (d < 64) ? -kraw[base + d + 64] : kraw[base + d - 64];
        const float qo = qv * c + qh * s;
        const float ko = kv * c + kh * s;
        qrope[base + d] = qo;
        qsh[d] = qo;
        ksh[d] = ko;

        float4 kq = *(const float4*)(&key_q[(size_t)(base + d) * 4]);
        red[d] = make_float4(qo * kq.x, qo * kq.y, qo * kq.z, qo * kq.w);
    }
    __syncthreads();
    for (int st = 64; st; st >>= 1) {
        if (tid < st) {
            red[tid].x += red[tid + st].x; red[tid].y += red[tid + st].y;
            red[tid].z += red[tid + st].z; red[tid].w += red[tid + st].w;
        }
        __syncthreads();
    }
    if (tid == 0) *(float4*)(&qr[bh * 4]) = red[0];

    // tail scores: s in [NSQ, NSQ+64)
    const int lane = tid & 63, wave = tid >> 6;
    for (int t = wave; t < 64; t += 4) {
        const float* row = (t < 63) ? &kfull[((size_t)bh * NSF + t) * ND] : ksh;
        const int d = lane * 2;
        float v = qsh[d] * row[d] + qsh[d + 1] * row[d + 1];
#pragma unroll
        for (int off = 32; off; off >>= 1) v += __shfl_down(v, off, 64);
        if (lane == 0) scores[(size_t)bh * NST + NSQ + t] = v * 0.08838834764831845f;
    }
}

// ---------------------------------------------------------------------------
// Quantized-K scores. Each thread: 4 consecutive s via nt int4 loads.
// grid = NBH*4 (chunks of 1024 s), 256 threads.
// ---------------------------------------------------------------------------
__global__ __launch_bounds__(256) void scores_quant_kernel(const int*   __restrict__ kq,
                                                           const float* __restrict__ ksc,
                                                           const float* __restrict__ kmn,
                                                           const float* __restrict__ keyp,
                                                           const float* __restrict__ qrope,
                                                           const float* __restrict__ qr,
                                                           float* __restrict__ scores) {
    const int bh    = blockIdx.x >> 2;
    const int chunk = blockIdx.x & 3;
    const int tid   = threadIdx.x;
    const int gbase = chunk * 16;      // 16 groups of 64 per 1024-s chunk

    __shared__ float qs[128][16];      // q[d] * scale[d][g]
    __shared__ float mt[128][16];      // q[d] * mn[d][g] -> reduced over d

    {
        const int d = tid >> 1, half = tid & 1;
        const float q = qrope[bh * ND + d];
        const float* scp = &ksc[((size_t)bh * ND + d) * 64 + gbase + half * 8];
        const float* mnp = &kmn[((size_t)bh * ND + d) * 64 + gbase + half * 8];
        v4f a = __builtin_nontemporal_load((const v4f*)(scp));
        v4f c = __builtin_nontemporal_load((const v4f*)(scp + 4));
        qs[d][half * 8 + 0] = q * a.x; qs[d][half * 8 + 1] = q * a.y;
        qs[d][half * 8 + 2] = q * a.z; qs[d][half * 8 + 3] = q * a.w;
        qs[d][half * 8 + 4] = q * c.x; qs[d][half * 8 + 5] = q * c.y;
        qs[d][half * 8 + 6] = q * c.z; qs[d][half * 8 + 7] = q * c.w;
        v4f m0 = __builtin_nontemporal_load((const v4f*)(mnp));
        v4f m1 = __builtin_nontemporal_load((const v4f*)(mnp + 4));
        mt[d][half * 8 + 0] = q * m0.x; mt[d][half * 8 + 1] = q * m0.y;
        mt[d][half * 8 + 2] = q * m0.z; mt[d][half * 8 + 3] = q * m0.w;
        mt[d][half * 8 + 4] = q * m1.x; mt[d][half * 8 + 5] = q * m1.y;
        mt[d][half * 8 + 6] = q * m1.z; mt[d][half * 8 + 7] = q * m1.w;
    }
    __syncthreads();
    for (int st = 64; st; st >>= 1) {
        for (int idx = tid; idx < st * 16; idx += 256) {
            const int dd = idx >> 4, g = idx & 15;
            mt[dd][g] += mt[dd + st][g];
        }
        __syncthreads();
    }

    const int s0 = chunk * 1024 + tid * 4;
    const int g  = tid >> 4;           // (tid*4)/64
    const int* kcol = kq + (size_t)bh * ND * NSQ + s0;

    float a0 = 0.f, a1 = 0.f, a2 = 0.f, a3 = 0.f;
#pragma unroll 8
    for (int d = 0; d < ND; ++d) {
        v4i c = __builtin_nontemporal_load((const v4i*)&kcol[(size_t)d * NSQ]);
        const float w = qs[d][g];
        a0 += w * (float)c.x; a1 += w * (float)c.y;
        a2 += w * (float)c.z; a3 += w * (float)c.w;
    }
    const float mnsum = mt[0][g];
    const float4 q4 = *(const float4*)(&qr[bh * 4]);

    float out[4] = {a0, a1, a2, a3};
#pragma unroll
    for (int j = 0; j < 4; ++j) {
        v4f kp = __builtin_nontemporal_load(
                     (const v4f*)&keyp[((size_t)bh * NSQ + s0 + j) * 4]);
        out[j] = (out[j] + mnsum + q4.x * kp.x + q4.y * kp.y + q4.z * kp.z + q4.w * kp.w)
                 * 0.08838834764831845f;
    }
    *(float4*)(&scores[(size_t)bh * NST + s0]) = make_float4(out[0], out[1], out[2], out[3]);
}

// ---------------------------------------------------------------------------
// Softmax stats only: stats[bh] = {max, 1/sum}. grid = 128, 256 threads.
// ---------------------------------------------------------------------------
__global__ __launch_bounds__(256) void softmax_stats_kernel(const float* __restrict__ scores,
                                                            float* __restrict__ stats) {
    const int bh = blockIdx.x;
    const int tid = threadIdx.x;
    const float* row = scores + (size_t)bh * NST;
    __shared__ float red[256];

    float m = -1e30f;
    for (int i = tid; i < NST; i += 256) m = fmaxf(m, row[i]);
    red[tid] = m; __syncthreads();
    for (int st = 128; st; st >>= 1) { if (tid < st) red[tid] = fmaxf(red[tid], red[tid + st]); __syncthreads(); }
    m = red[0]; __syncthreads();

    float sum = 0.f;
    for (int i = tid; i < NST; i += 256) sum += expf(row[i] - m);
    red[tid] = sum; __syncthreads();
    for (int st = 128; st; st >>= 1) { if (tid < st) red[tid] += red[tid + st]; __syncthreads(); }
    if (tid == 0) { stats[bh * 2] = m; stats[bh * 2 + 1] = 1.f / red[0]; }
}

// ---------------------------------------------------------------------------
// Quantized-V partials with inline softmax. 256 threads = 8 s-rows x 32 lanes.
// grid = NBH*16 (splits of 256 s), 256 threads.
// ---------------------------------------------------------------------------
__global__ __launch_bounds__(256) void pv_quant_kernel(const int*   __restrict__ vq,
                                                       const float* __restrict__ vsc,
                                                       const float* __restrict__ vmn,
                                                       const float* __restrict__ valq,
                                                       const float* __restrict__ scores,
                                                       const float* __restrict__ stats,
                                                       float* __restrict__ pout,
                                                       float* __restrict__ ppr) {
    const int bh    = blockIdx.x >> 4;
    const int split = blockIdx.x & 15;
    const int tid   = threadIdx.x;
    const int sbase = split * 256;

    __shared__ float  psc[256][2];     // p[k] * scale[k][g]
    __shared__ float4 red4[256];       // -> ppr
    __shared__ float2 red2[256];       // -> pmn
    __shared__ float4 racc[256];
    __shared__ float  pmn2[2];

    {
        const int s = sbase + tid;
        const float m = stats[bh * 2], invZ = stats[bh * 2 + 1];
        const float pv = expf(scores[(size_t)bh * NST + s] - m) * invZ;
        float2 sc = *(const float2*)(&vsc[((size_t)bh * NSQ + s) * 2]);
        float2 mn = *(const float2*)(&vmn[((size_t)bh * NSQ + s) * 2]);
        psc[tid][0] = pv * sc.x;
        psc[tid][1] = pv * sc.y;
        red2[tid] = make_float2(pv * mn.x, pv * mn.y);
        v4f v4 = __builtin_nontemporal_load((const v4f*)&valq[((size_t)bh * NSQ + s) * 4]);
        red4[tid] = make_float4(pv * v4.x, pv * v4.y, pv * v4.z, pv * v4.w);
    }
    __syncthreads();
    for (int st = 128; st; st >>= 1) {
        if (tid < st) {
            red4[tid].x += red4[tid + st].x; red4[tid].y += red4[tid + st].y;
            red4[tid].z += red4[tid + st].z; red4[tid].w += red4[tid + st].w;
            red2[tid].x += red2[tid + st].x; red2[tid].y += red2[tid + st].y;
        }
        __syncthreads();
    }
    if (tid == 0) {
        *(float4*)(&ppr[((size_t)bh * 16 + split) * 4]) = red4[0];
        pmn2[0] = red2[0].x; pmn2[1] = red2[0].y;
    }

    const int r      = tid >> 5;       // s-row within group of 8
    const int lane32 = tid & 31;
    const int d4     = lane32 * 4;
    const int g      = lane32 >> 4;    // d4/64

    const int* vbase = vq + ((size_t)bh * NSQ + sbase) * ND + d4;

    float4 acc = make_float4(0.f, 0.f, 0.f, 0.f);
#pragma unroll 8
    for (int k0 = 0; k0 < 256; k0 += 8) {
        const int kk = k0 + r;
        v4i c = __builtin_nontemporal_load((const v4i*)&vbase[(size_t)kk * ND]);
        const float w = psc[kk][g];
        acc.x += w * (float)c.x; acc.y += w * (float)c.y;
        acc.z += w * (float)c.z; acc.w += w * (float)c.w;
    }
    __syncthreads();                   // ensures pmn2 visible below
    racc[tid] = acc;
    __syncthreads();
    for (int st = 128; st >= 32; st >>= 1) {
        if (tid < st) {
            racc[tid].x += racc[tid + st].x; racc[tid].y += racc[tid + st].y;
            racc[tid].z += racc[tid + st].z; racc[tid].w += racc[tid + st].w;
        }
        __syncthreads();
    }
    if (tid < 32) {
        float4 t = racc[tid];
        const float mn = pmn2[tid >> 4];
        t.x += mn; t.y += mn; t.z += mn; t.w += mn;
        *(float4*)(&pout[((size_t)bh * 16 + split) * ND + tid * 4]) = t;
    }
}

// ---------------------------------------------------------------------------
// Finish: reduce split partials, add low-rank V and full-precision V tail.
// grid = 128 (bh), 128 threads (d).
// ---------------------------------------------------------------------------
__global__ __launch_bounds__(128) void pv_finish_kernel(const float* __restrict__ pout,
                                                        const float* __restrict__ ppr,
                                                        const float* __restrict__ valp,
                                                        const float* __restrict__ vfull,
                                                        const float* __restrict__ vraw,
                                                        const float* __restrict__ scores,
                                                        const float* __restrict__ stats,
                                                        float* __restrict__ attn_out) {
    const int bh = blockIdx.x;
    const int d  = threadIdx.x;

    float acc = 0.f;
#pragma unroll
    for (int sp = 0; sp < 16; ++sp) acc += pout[((size_t)bh * 16 + sp) * ND + d];

    float prx = 0.f, pry = 0.f, prz = 0.f, prw = 0.f;
#pragma unroll
    for (int sp = 0; sp < 16; ++sp) {
        float4 t = *(const float4*)(&ppr[((size_t)bh * 16 + sp) * 4]);
        prx += t.x; pry += t.y; prz += t.z; prw += t.w;
    }
    float4 vp = *(const float4*)(&valp[((size_t)bh * ND + d) * 4]);
    acc += prx * vp.x + pry * vp.y + prz * vp.z + prw * vp.w;

    const float m = stats[bh * 2], invZ = stats[bh * 2 + 1];
    const float* sf = scores + (size_t)bh * NST + NSQ;
    for (int t = 0; t < NSF; ++t) {
        const float p = expf(sf[t] - m) * invZ;
        acc += p * __builtin_nontemporal_load(&vfull[((size_t)bh * NSF + t) * ND + d]);
    }
    acc += expf(sf[NSF] - m) * invZ * vraw[bh * ND + d];

    attn_out[bh * ND + d] = acc;
}

// ---------------------------------------------------------------------------
extern "C" void kernel_launch(void* const* d_in, const int* in_sizes, int n_in,
                              void* d_out, int out_size, void* d_ws, size_t ws_size,
                              hipStream_t stream) {
    const float* hs    = (const float*)d_in[0];
    const float* wq    = (const float*)d_in[1];
    const float* wk    = (const float*)d_in[2];
    const float* wv    = (const float*)d_in[3];
    const float* wo    = (const float*)d_in[4];
    const int*   pos   = (const int*)  d_in[5];
    const int*   kq    = (const int*)  d_in[6];
    const float* ksc   = (const float*)d_in[7];
    const float* kmn   = (const float*)d_in[8];
    const float* kfull = (const float*)d_in[9];
    const float* keyp  = (const float*)d_in[10];
    const float* keyq  = (const float*)d_in[11];
    const int*   vq    = (const int*)  d_in[12];
    const float* vsc   = (const float*)d_in[13];
    const float* vmn   = (const float*)d_in[14];
    const float* vfull = (const float*)d_in[15];
    const float* valq  = (const float*)d_in[16];
    const float* valp  = (const float*)d_in[17];

    float* ws = (float*)d_ws;
    float* q_raw   = ws;                 // 16384
    float* k_raw   = q_raw  + 16384;     // 16384
    float* v_raw   = k_raw  + 16384;     // 16384
    float* q_rope  = v_raw  + 16384;     // 16384
    float* qr      = q_rope + 16384;     // 512
    float* stats   = qr     + 512;       // 256
    float* scores  = stats  + 256;       // 128*4160 = 532480
    float* pout    = scores + 532480;    // 128*16*128 = 262144
    float* ppr     = pout   + 262144;    // 128*16*4 = 8192
    float* attno   = ppr    + 8192;      // 16384

    gemv8_qkv_kernel<<<1536, 256, 0, stream>>>(wq, wk, wv, hs, q_raw, k_raw, v_raw);

    rope_full_kernel<<<128, 256, 0, stream>>>(q_raw, k_raw, pos, keyq, kfull,
                                              q_rope, qr, scores);

    scores_quant_kernel<<<512, 256, 0, stream>>>(kq, ksc, kmn, keyp, q_rope, qr, scores);

    softmax_stats_kernel<<<128, 256, 0, stream>>>(scores, stats);

    pv_quant_kernel<<<2048, 256, 0, stream>>>(vq, vsc, vmn, valq, scores, stats, pout, ppr);
    pv_finish_kernel<<<128, 128, 0, stream>>>(pout, ppr, valp, vfull, v_raw, scores, stats, attno);

    gemv8_kernel<<<512, 256, 0, stream>>>(wo, attno, (float*)d_out);
}